// Round 18
// baseline (103.447 us; speedup 1.0000x reference)
//
#include <hip/hip_runtime.h>
#include <math.h>

#define AFWD 0.999f
#define ONE_MINUS_A (1.0f - 0.999f)
#define KCOEF (0.999f * (1.0f - 0.999f))
#define EPSV 1e-5f

typedef float floatx4 __attribute__((ext_vector_type(4)));

// ===========================================================================
// Two-dispatch online normalization, C=64 chunks (CH=128).
// R16 (C=128) failed because redundant walk traffic scales as C^2:
//   C=128 -> 400 MB L2/L3 reads + 6 MB table > 4 MB per-XCD L2  (+10.8us)
//   C=64  ->  99 MB              + 3 MB table fits per-XCD L2
// D1 (passA): per (chunk c, col4) summaries with chunk-start M=0.
// D2 (passWC): walk chunk-transfer maps 0..c-1 from (m,var) (proven algebra),
//   then replay chunk c exactly and NT-store out (R10-proven store policy).
// No cross-block sync/atomics (all such designs measured 0.9-3 TB/s).
// ===========================================================================

__global__ __launch_bounds__(256) void
passA(const float* __restrict__ x, float* __restrict__ Bmu,
      float* __restrict__ See, float* __restrict__ Te, int L4, int CH) {
  int idx  = blockIdx.x * blockDim.x + threadIdx.x;
  int col4 = idx % L4;
  int c    = idx / L4;
  const floatx4* xv = (const floatx4*)x;
  int base = c * CH * L4 + col4;

  float mu[4] = {0.f, 0.f, 0.f, 0.f};
  float s[4]  = {0.f, 0.f, 0.f, 0.f};
  float t[4]  = {0.f, 0.f, 0.f, 0.f};
#pragma unroll 4
  for (int i = 0; i < CH; ++i) {
    floatx4 v = xv[base + i * L4];
#pragma unroll
    for (int k = 0; k < 4; ++k) {
      float e = v[k] - mu[k];
      s[k] = fmaf(AFWD, s[k], e * e);
      t[k] += e;
      mu[k] = fmaf(ONE_MINUS_A, e, mu[k]);
    }
  }
  int o = c * L4 + col4;
  floatx4 om = {mu[0], mu[1], mu[2], mu[3]};
  floatx4 os = {s[0], s[1], s[2], s[3]};
  floatx4 ot = {t[0], t[1], t[2], t[3]};
  ((floatx4*)Bmu)[o] = om;
  ((floatx4*)See)[o] = os;
  ((floatx4*)Te)[o]  = ot;
}

__global__ __launch_bounds__(256) void
passWC(const float* __restrict__ x, const float* __restrict__ m,
       const float* __restrict__ var, const float* __restrict__ Bmu,
       const float* __restrict__ See, const float* __restrict__ Te,
       float* __restrict__ out, int L4, int CH,
       float A, float c_eg, float Sgg) {
  int idx  = blockIdx.x * blockDim.x + threadIdx.x;
  int col4 = idx % L4;
  int c    = idx / L4;
  const floatx4* xv   = (const floatx4*)x;
  const floatx4* bmu4 = (const floatx4*)Bmu;
  const floatx4* see4 = (const floatx4*)See;
  const floatx4* te4  = (const floatx4*)Te;
  floatx4* ov = (floatx4*)out;
  int base = c * CH * L4 + col4;

  // ---- walk: chunks 0..c-1 from (m,var); 3 MB table is L2-resident ----
  float M[4], V[4];
  {
    floatx4 m4 = ((const floatx4*)m)[col4];
    floatx4 v4 = ((const floatx4*)var)[col4];
#pragma unroll
    for (int k = 0; k < 4; ++k) { M[k] = m4[k]; V[k] = v4[k]; }
  }
#pragma unroll 4
  for (int cc = 0; cc < c; ++cc) {
    int o = cc * L4 + col4;
    floatx4 bb = bmu4[o];
    floatx4 ss = see4[o];
    floatx4 tt = te4[o];
#pragma unroll
    for (int k = 0; k < 4; ++k) {
      float sum = fmaf(M[k] * M[k], Sgg,
                       fmaf(-2.0f * c_eg * M[k], tt[k], ss[k]));
      V[k] = fmaf(A, V[k], KCOEF * sum);
      M[k] = fmaf(A, M[k], bb[k]);
    }
  }

  // ---- replay chunk c exactly; NT stores protect x's L3 residency ----
#pragma unroll 4
  for (int i = 0; i < CH; ++i) {
    floatx4 v = xv[base + i * L4];
    floatx4 oe;
#pragma unroll
    for (int k = 0; k < 4; ++k) {
      float d = v[k] - M[k];
      oe[k] = d * rsqrtf(V[k] + EPSV);
      V[k] = fmaf(AFWD, V[k], KCOEF * (d * d));
      M[k] = fmaf(ONE_MINUS_A, d, M[k]);
    }
    __builtin_nontemporal_store(oe, &ov[base + i * L4]);
  }
}

extern "C" void kernel_launch(void* const* d_in, const int* in_sizes, int n_in,
                              void* d_out, int out_size, void* d_ws, size_t ws_size,
                              hipStream_t stream) {
  const float* x   = (const float*)d_in[0];
  const float* m   = (const float*)d_in[1];
  const float* var = (const float*)d_in[2];
  float* out = (float*)d_out;

  int L  = in_sizes[1];          // 4096
  int N  = in_sizes[0] / L;      // 8192
  int L4 = L / 4;

  int C = 64;                    // CH=128; walk traffic ~ C^2, table 3 MB
  while (C > 1 &&
         ((size_t)3 * C * L * sizeof(float) > ws_size || (N % C) != 0))
    C >>= 1;
  int CH = N / C;

  double a = 0.999;
  float A    = (float)pow(a, (double)CH);
  float c_eg = (float)pow(a, (double)(CH - 1));
  float Sgg  = (float)(pow(a, (double)(CH - 1)) * (1.0 - pow(a, (double)CH)) / (1.0 - a));

  float* ws  = (float*)d_ws;
  size_t CL  = (size_t)C * L;
  float* Bmu = ws;
  float* See = ws + CL;
  float* Te  = ws + 2 * CL;

  int gridBlocks = (C * L4) / 256;   // 256
  passA<<<gridBlocks, 256, 0, stream>>>(x, Bmu, See, Te, L4, CH);
  passWC<<<gridBlocks, 256, 0, stream>>>(x, m, var, Bmu, See, Te, out, L4, CH,
                                         A, c_eg, Sgg);
}